// Round 1
// baseline (191.142 us; speedup 1.0000x reference)
//
#include <hip/hip_runtime.h>

#define BATCH 8192
#define IDIM 256
#define ODIM 256
#define KGRID 64

#define NCHUNK 4
#define IPC 64            // i-values per K-chunk
#define BM 128
#define THREADS 512
#define RG_TOT 4096       // (2*IDIM*KGRID)/8

typedef __attribute__((ext_vector_type(8))) short short8;
typedef __attribute__((ext_vector_type(4))) float float4v;
typedef __attribute__((ext_vector_type(4))) unsigned int uint4v;

// pack two f32 -> (bf16(c) | bf16(s)<<16), RTNE
__device__ __forceinline__ unsigned int bf16pack(float c, float s) {
    union { float f; unsigned int u; } a, b;
    a.f = c; b.f = s;
    unsigned int ua = a.u + (0x7fffu + ((a.u >> 16) & 1u));
    unsigned int ub = b.u + (0x7fffu + ((b.u >> 16) & 1u));
    return (ua >> 16) | (ub & 0xffff0000u);
}

// W[2][256][256][64] f32  ->  Bw[rg=4096][j=256][8] bf16
// r = i*128 + 2k + d ; rg = r/8 = i*16 + k/4 ; e = 2*(k%4) + d
// source float4 index for (rg, j, d): d*1048576 + j*4096 + rg   (since 4*rg = i*64 + 4*(k/4))
__global__ void prep_w(const float4v* __restrict__ W, uint4v* __restrict__ Bw) {
    int tid = blockIdx.x * 256 + threadIdx.x;   // 1,048,576 threads
    int rg = tid >> 8;
    int j = tid & 255;
    float4v c4 = W[j * 4096 + rg];
    float4v s4 = W[1048576 + j * 4096 + rg];
    uint4v o;
    o.x = bf16pack(c4.x, s4.x);
    o.y = bf16pack(c4.y, s4.y);
    o.z = bf16pack(c4.z, s4.z);
    o.w = bf16pack(c4.w, s4.w);
    Bw[rg * 256 + j] = o;   // coalesced 16B stores, j fastest
}

__global__ __launch_bounds__(THREADS) void kan_main(
    const float* __restrict__ x,
    const short* __restrict__ Bw,
    float* __restrict__ part)
{
    __shared__ __align__(16) float x_lds[IPC][BM];          // 32 KB, transposed x tile
    __shared__ __align__(16) short A_lds[2][16 * BM * 8];   // 64 KB, dbuf feature tiles

    const int bx = blockIdx.x;
    const int chunk = bx & 3;          // K-chunk 0..3
    const int mt = bx >> 2;            // M-tile 0..63
    const int b0 = mt * BM;
    const int i0 = chunk * IPC;
    const int t = threadIdx.x;
    const int lane = t & 63;
    const int wave = t >> 6;           // 0..7
    const int wm = wave >> 2;          // 0..1  (M half)
    const int wn = wave & 3;           // 0..3  (N quarter)

    // ---- stage x tile transposed: x_lds[i_local][row] ----
    {
        const int row = t & 127;
        const int ig = t >> 7;         // 0..3 -> 16 i's each
        const float4v* src = (const float4v*)(x + (size_t)(b0 + row) * IDIM + i0 + ig * 16);
        float4v v[4];
        #pragma unroll
        for (int q = 0; q < 4; ++q) v[q] = src[q];
        #pragma unroll
        for (int q = 0; q < 4; ++q) {
            #pragma unroll
            for (int u = 0; u < 4; ++u)
                x_lds[ig * 16 + q * 4 + u][row] = v[q][u];
        }
    }
    __syncthreads();

    // features for local i index iloc -> Abuf laid out [16 rg][128 row][8]
    auto feats = [&](short* Abuf, int iloc) {
        const int row = t >> 2;        // 0..127
        const int sub = t & 3;         // 16 k's per thread
        float xv = x_lds[iloc][row];
        float xk = xv * 0.15915494309189535f;   // x / (2*pi)
        uint4v* slots = (uint4v*)Abuf;
        #pragma unroll
        for (int g = 0; g < 4; ++g) {
            const int kb = sub * 16 + g * 4;    // k code base (mult = kb+1+u)
            unsigned int w[4];
            #pragma unroll
            for (int u = 0; u < 4; ++u) {
                float rev = xk * (float)(kb + 1 + u);
                rev = rev - floorf(rev);
                float cv = __builtin_amdgcn_cosf(rev);   // cos(2*pi*rev)
                float sv = __builtin_amdgcn_sinf(rev);
                w[u] = bf16pack(cv, sv);
            }
            uint4v o; o.x = w[0]; o.y = w[1]; o.z = w[2]; o.w = w[3];
            slots[(sub * 4 + g) * BM + row] = o;
        }
    };

    // per-thread B pointer (16B slot granularity): slot = rg*256 + col
    const short8* Bp = (const short8*)Bw
        + (size_t)(chunk * 1024 + (lane >> 4)) * 256 + wn * 64 + (lane & 15);

    short8 bB[2][4];
    #pragma unroll
    for (int f = 0; f < 4; ++f) bB[0][f] = Bp[f * 16];

    feats(A_lds[0], 0);
    __syncthreads();

    float4v acc[4][4];
    #pragma unroll
    for (int m = 0; m < 4; ++m)
        #pragma unroll
        for (int f = 0; f < 4; ++f)
            acc[m][f] = (float4v)(0.0f);

    const int aoff = (lane >> 4) * BM + wm * 64 + (lane & 15);

    for (int it = 0; it < IPC; ++it) {
        const int cur = it & 1;
        const short8* Ab = (const short8*)(A_lds[cur]);
        #pragma unroll
        for (int kk = 0; kk < 4; ++kk) {
            const int s = it * 4 + kk;
            const int sp = (s + 1 < 256) ? (s + 1) : 255;
            #pragma unroll
            for (int f = 0; f < 4; ++f)
                bB[(kk + 1) & 1][f] = Bp[(size_t)sp * 1024 + f * 16];
            short8 a[4];
            #pragma unroll
            for (int m = 0; m < 4; ++m)
                a[m] = Ab[(kk * 4) * BM + aoff + m * 16];
            #pragma unroll
            for (int m = 0; m < 4; ++m)
                #pragma unroll
                for (int f = 0; f < 4; ++f)
                    acc[m][f] = __builtin_amdgcn_mfma_f32_16x16x32_bf16(
                        a[m], bB[kk & 1][f], acc[m][f], 0, 0, 0);
        }
        if (it + 1 < IPC) feats(A_lds[cur ^ 1], it + 1);
        __syncthreads();
    }

    // ---- store partials: part[chunk][b][j] ----
    // C/D layout (m89): col = lane&15, row = (lane>>4)*4 + v
    float* pc = part + (size_t)chunk * (BATCH * ODIM)
              + (size_t)(b0 + wm * 64 + ((lane >> 4) * 4)) * ODIM
              + wn * 64 + (lane & 15);
    #pragma unroll
    for (int m = 0; m < 4; ++m)
        #pragma unroll
        for (int v = 0; v < 4; ++v)
            #pragma unroll
            for (int f = 0; f < 4; ++f)
                pc[(size_t)(m * 16 + v) * ODIM + f * 16] = acc[m][f][v];
}

__global__ void reduce_bias(const float4v* __restrict__ part,
                            const float4v* __restrict__ bias,
                            float4v* __restrict__ out)
{
    const int tid = blockIdx.x * 256 + threadIdx.x;   // 524288 float4s
    const int Q = BATCH * ODIM / 4;
    float4v r = part[tid] + part[tid + Q] + part[tid + 2 * Q] + part[tid + 3 * Q];
    r += bias[tid & 63];
    out[tid] = r;
}

extern "C" void kernel_launch(void* const* d_in, const int* in_sizes, int n_in,
                              void* d_out, int out_size, void* d_ws, size_t ws_size,
                              hipStream_t stream)
{
    const float* x = (const float*)d_in[0];
    const float* W = (const float*)d_in[1];
    const float* bias = (const float*)d_in[2];
    float* out = (float*)d_out;

    // workspace layout: Bw bf16 [4096][256][8] = 16.78 MB, then partials 33.55 MB
    short* Bw = (short*)d_ws;
    float* part = (float*)((char*)d_ws + (size_t)RG_TOT * 256 * 16);

    prep_w<<<4096, 256, 0, stream>>>((const float4v*)W, (uint4v*)Bw);
    kan_main<<<256, THREADS, 0, stream>>>(x, Bw, part);
    reduce_bias<<<(BATCH * ODIM / 4) / 256, 256, 0, stream>>>(
        (const float4v*)part, (const float4v*)bias, (float4v*)out);
}